// Round 3
// baseline (219.132 us; speedup 1.0000x reference)
//
#include <hip/hip_runtime.h>

// Problem constants (from reference)
#define BATCH 4
#define POINT_NUM 50000
#define NPTS (BATCH * POINT_NUM)   // 200000
#define NVOX 150000
#define FEAT 256

// k0: zero the referenced-voxel mask (d_ws is poisoned 0xAA each replay).
__global__ __launch_bounds__(256) void zero_mask_kernel(unsigned char* __restrict__ mask) {
    const int i = blockIdx.x * blockDim.x + threadIdx.x;           // word index
    unsigned int* m32 = (unsigned int*)mask;
    const int nwords = (NVOX + 3) / 4;
    if (i < nwords) m32[i] = 0u;
}

// k1: mark voxels referenced by any point. Races are benign (all write 1).
__global__ __launch_bounds__(256) void mark_kernel(
    const int* __restrict__ idx, unsigned char* __restrict__ mask) {
    const int p = blockIdx.x * blockDim.x + threadIdx.x;
    if (p < NPTS) mask[idx[p]] = 1;
}

// k2: project referenced voxel rows through the 2x256 linear layer.
// One wave per voxel row; sequential streaming reads; unreferenced rows
// skipped (wave-uniform branch) -> ~26% traffic saved for uniform idx.
__global__ __launch_bounds__(256) void project_kernel(
    const float* __restrict__ feat,   // [NVOX, FEAT]
    const float* __restrict__ w,      // [2, FEAT]
    const float* __restrict__ bias,   // [2]
    const unsigned char* __restrict__ mask,
    float* __restrict__ s0,           // [NVOX] scratch
    float* __restrict__ s1)           // [NVOX] scratch
{
    const int wave = (blockIdx.x * blockDim.x + threadIdx.x) >> 6;
    const int lane = threadIdx.x & 63;
    if (wave >= NVOX) return;
    if (!mask[wave]) return;          // wave-uniform: all 64 lanes same voxel

    const float4 w0 = ((const float4*)(w))[lane];
    const float4 w1 = ((const float4*)(w + FEAT))[lane];
    const float4 f  = ((const float4*)(feat + (size_t)wave * FEAT))[lane];

    float a = f.x * w0.x + f.y * w0.y + f.z * w0.z + f.w * w0.w;
    float b = f.x * w1.x + f.y * w1.y + f.z * w1.z + f.w * w1.w;

    #pragma unroll
    for (int off = 32; off > 0; off >>= 1) {
        a += __shfl_down(a, off, 64);
        b += __shfl_down(b, off, 64);
    }

    if (lane == 0) {
        s0[wave] = a + bias[0];
        s1[wave] = b + bias[1];
    }
}

// k3: per-point gather of the 2 projected scores (600 KB tables, L2-resident).
__global__ __launch_bounds__(256) void gather_kernel(
    const int* __restrict__ idx,
    const float* __restrict__ s0,
    const float* __restrict__ s1,
    float* __restrict__ out)          // [2, NPTS]
{
    const int p = blockIdx.x * blockDim.x + threadIdx.x;
    if (p >= NPTS) return;
    const int v = idx[p];
    out[p]        = s0[v];
    out[NPTS + p] = s1[v];
}

extern "C" void kernel_launch(void* const* d_in, const int* in_sizes, int n_in,
                              void* d_out, int out_size, void* d_ws, size_t ws_size,
                              hipStream_t stream) {
    const float* feat = (const float*)d_in[0];
    const int*   idx  = (const int*)d_in[1];
    const float* w    = (const float*)d_in[2];
    const float* bias = (const float*)d_in[3];
    float* out = (float*)d_out;

    float* s0 = (float*)d_ws;                       // [NVOX]
    float* s1 = s0 + NVOX;                          // [NVOX]
    unsigned char* mask = (unsigned char*)(s1 + NVOX);  // [NVOX] bytes

    const int nwords = (NVOX + 3) / 4;
    zero_mask_kernel<<<(nwords + 255) / 256, 256, 0, stream>>>(mask);

    mark_kernel<<<(NPTS + 255) / 256, 256, 0, stream>>>(idx, mask);

    const int blocks1 = (NVOX * 64 + 255) / 256;    // one wave per voxel
    project_kernel<<<blocks1, 256, 0, stream>>>(feat, w, bias, mask, s0, s1);

    gather_kernel<<<(NPTS + 255) / 256, 256, 0, stream>>>(idx, s0, s1, out);
}